// Round 8
// baseline (734.337 us; speedup 1.0000x reference)
//
#include <hip/hip_runtime.h>
#include <hip/hip_bf16.h>

#define HWs 50176      // 224*224
#define WID 224
#define OHW 200704     // 448*448
#define XP 448         // bytes per pixel in X format: [hi 112ch][lo 112ch] bf16

typedef __attribute__((ext_vector_type(8))) short s16x8;
typedef __attribute__((ext_vector_type(4))) float f32x4;

static __device__ __forceinline__ unsigned short f2bf(float x) {
  unsigned u = __float_as_uint(x);
  unsigned r = (u + 0x7fffu + ((u >> 16) & 1u)) >> 16;   // RNE
  return (unsigned short)r;
}
static __device__ __forceinline__ float bf2f(unsigned short b) {
  return __uint_as_float(((unsigned)b) << 16);
}

// ---------------- K0: pack conv weights into MFMA B-fragment order, split bf16 hi/lo.
// frag_id = l*288 + t*32 + ck*8 + nt; B[k][n]: n = nt*16+(lane&15), ic = ck*32+(lane>>4)*8+e.
// oc>=100 or ic>=100 -> 0 (this zero-padding is what makes the A-side clamp safe).
__global__ void k_wt(const float* __restrict__ w_head, const float* __restrict__ w_blk,
                     unsigned short* __restrict__ bw) {
  int gid = blockIdx.x * 256 + threadIdx.x;          // 720*256 == 184320 exact
  int frag = gid >> 7, rr = gid & 127;
  int spl = rr >> 6, lane = rr & 63;
  int l = frag / 288, q = frag - l * 288;
  int t = q / 32, q2 = q - t * 32;
  int ck = q2 >> 3, nt = q2 & 7;
  int oc = nt * 16 + (lane & 15);
  int kg = lane >> 4;
  const float* src = (l == 0) ? w_head : (w_blk + (size_t)(l - 1) * 90000);
  s16x8 outv;
  #pragma unroll
  for (int e = 0; e < 8; ++e) {
    int ic = ck * 32 + kg * 8 + e;
    float w = (oc < 100 && ic < 100) ? src[oc * 900 + ic * 9 + t] : 0.f;
    unsigned short h = f2bf(w);
    unsigned short lo = f2bf(w - bf2f(h));
    outv[e] = (short)(spl ? lo : h);
  }
  ((s16x8*)bw)[gid] = outv;
}

// ---------------- K0c: transpose w_last [36][500] -> wlT [500][36]
__global__ void k_wlT(const float* __restrict__ wlast, float* __restrict__ wlT) {
  int i = blockIdx.x * 256 + threadIdx.x;
  if (i < 18000) {
    int il = i / 36, o = i - il * 36;
    wlT[i] = wlast[o * 500 + il];
  }
}

// ---------------- K0b: xlast = b_last (k_esum atomically accumulates). No aliasing now.
__global__ void k_binit(const float* __restrict__ blast, float* __restrict__ xlast) {
  int p = blockIdx.x * 256 + threadIdx.x;
  xlast[(size_t)blockIdx.y * HWs + p] = blast[blockIdx.y];
}

// ---------------- K1: bilinear warp + concat -> X-format (NHWC bf16 hi/lo).
// grid (196,4) x 256: yq computes 8 ch of f0w/f1w/fd; yq==0 also flow ch96-99 + pad 100-111.
__global__ void k_warp(const float* __restrict__ f0, const float* __restrict__ f1,
                       const float* __restrict__ fd, const float* __restrict__ fl,
                       unsigned char* __restrict__ xout) {
  int p = blockIdx.x * 256 + threadIdx.x;
  int yq = blockIdx.y;
  int y = p / WID, x = p - y * WID;
  float fx0 = fl[p];
  float fy0 = fl[HWs + p];
  float fx1 = fl[2 * HWs + p];
  float fy1 = fl[3 * HWs + p];
  unsigned char* dst = xout + (size_t)p * XP;

  auto cvstore = [&](int chbase, const float* ov) {   // 8 ch -> hi + lo s16x8 stores
    s16x8 hv, lv;
    #pragma unroll
    for (int e = 0; e < 8; ++e) {
      unsigned short h = f2bf(ov[e]);
      hv[e] = (short)h;
      lv[e] = (short)f2bf(ov[e] - bf2f(h));
    }
    *(s16x8*)(dst + chbase * 2) = hv;
    *(s16x8*)(dst + 224 + chbase * 2) = lv;
  };

  #pragma unroll
  for (int img = 0; img < 2; ++img) {
    const float* src = img ? f1 : f0;
    float fx = img ? fx1 : fx0;
    float fy = img ? fy1 : fy0;
    float px = (float)x + fx, py = (float)y + fy;
    float x0f = floorf(px), y0f = floorf(py);
    float wx = px - x0f, wy = py - y0f;
    int x0 = (int)fminf(fmaxf(x0f,       0.f), 223.f);
    int x1 = (int)fminf(fmaxf(x0f + 1.f, 0.f), 223.f);
    int y0 = (int)fminf(fmaxf(y0f,       0.f), 223.f);
    int y1 = (int)fminf(fmaxf(y0f + 1.f, 0.f), 223.f);
    float w00 = (1.f - wx) * (1.f - wy), w01 = wx * (1.f - wy);
    float w10 = (1.f - wx) * wy,         w11 = wx * wy;
    int i00 = y0 * WID + x0, i01 = y0 * WID + x1;
    int i10 = y1 * WID + x0, i11 = y1 * WID + x1;
    float ov[8];
    #pragma unroll
    for (int e = 0; e < 8; ++e) {
      const float* pl = src + (size_t)(yq * 8 + e) * HWs;
      ov[e] = w00 * pl[i00] + w01 * pl[i01] + w10 * pl[i10] + w11 * pl[i11];
    }
    cvstore(img * 32 + yq * 8, ov);
  }
  {
    float ov[8];
    #pragma unroll
    for (int e = 0; e < 8; ++e)
      ov[e] = fd[(size_t)(yq * 8 + e) * HWs + p];
    cvstore(64 + yq * 8, ov);
  }
  if (yq == 0) {
    float ov[8] = {fx0, fy0, fx1, fy1, 0.f, 0.f, 0.f, 0.f};
    cvstore(96, ov);
    float zz[8] = {0.f, 0.f, 0.f, 0.f, 0.f, 0.f, 0.f, 0.f};
    cvstore(104, zz);
  }
}

// ---------------- K2: MFMA split-bf16 3x3 conv — NO LDS, NO barriers.
// grid (7,56) x 256: tile 4 rows x 32 cols x 128 oc; wave (wr,wz) = 2 rows x 64 oc.
// A-fragments loaded DIRECTLY from X-format global (one 16B load per split):
// lane&15 -> pixel col, lane>>4 -> ic-octet. ic-octet clamped to <=96 (B zero-padded
// above ic 100, so clamped-A x 0 = 0). MFMA order identical to prior rounds
// (hi*b0, lo*b0, hi*b1) -> conv outputs bit-identical.
__global__ __launch_bounds__(256) void k_conv(
    const unsigned char* __restrict__ in, const unsigned short* __restrict__ bw,
    const float* __restrict__ avec, const float* __restrict__ mask,
    unsigned char* __restrict__ out) {
  const int tid = threadIdx.x;
  const int lane = tid & 63;
  const int wv = tid >> 6;
  const int wr = wv >> 1, wz = wv & 1;
  const int c0 = blockIdx.x * 32;
  const int r0 = blockIdx.y * 4;
  const int li = lane & 15, kg = lane >> 4;

  f32x4 acc[4][4];
  #pragma unroll
  for (int a = 0; a < 4; ++a)
    #pragma unroll
    for (int b = 0; b < 4; ++b) acc[a][b] = (f32x4){0.f, 0.f, 0.f, 0.f};

  const s16x8* bp = (const s16x8*)bw;
  s16x8 bcur[4][2], bnxt[4][2];
  #pragma unroll
  for (int nt = 0; nt < 4; ++nt)
    #pragma unroll
    for (int sp = 0; sp < 2; ++sp)
      bnxt[nt][sp] = bp[(((wz * 4 + nt) * 2 + sp) << 6) + lane];

  for (int ck = 0; ck < 4; ++ck) {
    int icb = ck * 32 + kg * 8;
    if (icb > 96) icb = 96;               // clamp into valid region (B zero beyond 100)
    const int icb2 = icb * 2;

    #pragma unroll
    for (int t = 0; t < 9; ++t) {
      #pragma unroll
      for (int nt = 0; nt < 4; ++nt) {
        bcur[nt][0] = bnxt[nt][0];
        bcur[nt][1] = bnxt[nt][1];
      }
      if (t < 8 || ck < 3) {
        int nf = (t < 8) ? (t + 1) * 32 + ck * 8 : (ck + 1) * 8;
        #pragma unroll
        for (int nt = 0; nt < 4; ++nt)
          #pragma unroll
          for (int sp = 0; sp < 2; ++sp)
            bnxt[nt][sp] = bp[(((nf + wz * 4 + nt) * 2 + sp) << 6) + lane];
      }
      const int dy = t / 3 - 1, dx = t - (t / 3) * 3 - 1;
      #pragma unroll
      for (int ms = 0; ms < 4; ++ms) {
        int row = r0 + wr * 2 + (ms >> 1) + dy;
        int col = c0 + (ms & 1) * 16 + li + dx;
        bool inb = ((unsigned)row < 224u) && ((unsigned)col < 224u);
        s16x8 ah = {0,0,0,0,0,0,0,0};
        s16x8 al = {0,0,0,0,0,0,0,0};
        if (inb) {
          const unsigned char* ap = in + (size_t)(row * WID + col) * XP + icb2;
          ah = *(const s16x8*)ap;
          al = *(const s16x8*)(ap + 224);
        }
        #pragma unroll
        for (int nt = 0; nt < 4; ++nt) {
          acc[ms][nt] = __builtin_amdgcn_mfma_f32_16x16x32_bf16(ah, bcur[nt][0], acc[ms][nt], 0, 0, 0);
          acc[ms][nt] = __builtin_amdgcn_mfma_f32_16x16x32_bf16(al, bcur[nt][0], acc[ms][nt], 0, 0, 0);
          acc[ms][nt] = __builtin_amdgcn_mfma_f32_16x16x32_bf16(ah, bcur[nt][1], acc[ms][nt], 0, 0, 0);
        }
      }
    }
  }

  // epilogue: PReLU * mask, convert to hi/lo, store X-format.
  // D: pixel = colb + reg (4 consecutive cols), oc = wz*64 + nt*16 + li.
  // oc 100-111 have acc==0 exactly (B zero-padded) -> stores zeros (keeps pad clean).
  float4 mv[4];
  #pragma unroll
  for (int ms = 0; ms < 4; ++ms) {
    int row = r0 + wr * 2 + (ms >> 1);
    int colb = c0 + (ms & 1) * 16 + kg * 4;
    mv[ms] = *(const float4*)&mask[row * WID + colb];
  }
  #pragma unroll
  for (int nt = 0; nt < 4; ++nt) {
    int oc = wz * 64 + nt * 16 + li;
    if (oc < 112) {
      float a = (oc < 100) ? avec[oc] : 0.f;
      #pragma unroll
      for (int ms = 0; ms < 4; ++ms) {
        int row = r0 + wr * 2 + (ms >> 1);
        int colb = c0 + (ms & 1) * 16 + kg * 4;
        f32x4 zv = acc[ms][nt];
        float vv[4] = {zv.x, zv.y, zv.z, zv.w};
        float mm[4] = {mv[ms].x, mv[ms].y, mv[ms].z, mv[ms].w};
        #pragma unroll
        for (int e = 0; e < 4; ++e) {
          float v = (vv[e] >= 0.f ? vv[e] : a * vv[e]) * mm[e];
          unsigned short h = f2bf(v);
          unsigned short lo = f2bf(v - bf2f(h));
          unsigned char* d = out + (size_t)(row * WID + colb + e) * XP + oc * 2;
          *(unsigned short*)d = h;
          *(unsigned short*)(d + 224) = lo;
        }
      }
    }
  }
}

// ---------------- K3: einsum partial from X-format buffers, K-split by layer.
// grid (784, nl) x 64: z picks buffer/layer; lane = pixel (448B contiguous row).
// v reconstructed as hi+lo (4e-6 rel); 36 atomicAdds into xlast (seeded with b_last).
__global__ __launch_bounds__(64) void k_esum(
    const unsigned char* __restrict__ X0, const unsigned char* __restrict__ X1,
    const unsigned char* __restrict__ X2, const float* __restrict__ wlT,
    float* __restrict__ xlast, int lbase) {
  int p = blockIdx.x * 64 + threadIdx.x;
  int z = blockIdx.y;
  const unsigned char* X = (z == 0) ? X0 : (z == 1) ? X1 : X2;
  const unsigned char* a = X + (size_t)p * XP;
  const float* w = wlT + (size_t)(lbase + z) * 3600;
  float acc[36];
  #pragma unroll
  for (int o = 0; o < 36; ++o) acc[o] = 0.f;
  for (int cb = 0; cb < 100; cb += 8) {
    s16x8 hv = *(const s16x8*)(a + cb * 2);
    s16x8 lv = *(const s16x8*)(a + 224 + cb * 2);
    int ne = (cb < 96) ? 8 : 4;                       // ch 96-99 real, 100+ skipped
    for (int e = 0; e < ne; ++e) {
      float v = bf2f((unsigned short)hv[e]) + bf2f((unsigned short)lv[e]);
      const float4* wp = (const float4*)(w + (cb + e) * 36);
      #pragma unroll
      for (int j = 0; j < 9; ++j) {
        float4 t = wp[j];
        acc[4*j]   = fmaf(t.x, v, acc[4*j]);
        acc[4*j+1] = fmaf(t.y, v, acc[4*j+1]);
        acc[4*j+2] = fmaf(t.z, v, acc[4*j+2]);
        acc[4*j+3] = fmaf(t.w, v, acc[4*j+3]);
      }
    }
  }
  #pragma unroll
  for (int o = 0; o < 36; ++o)
    atomicAdd(&xlast[(size_t)o * HWs + p], acc[o]);
}

// ---------------- K4: smn halves = conv3x3(xlast[4+h*16 .. +16], w_mask), fp64 accum.
__global__ void k_smn(const float* __restrict__ xlast, const float* __restrict__ wmask,
                      const float* __restrict__ bmask, float* __restrict__ smnh) {
  __shared__ float wm[288];
  int tid = threadIdx.x;
  int h = blockIdx.y;
  for (int j = tid; j < 288; j += 64) {
    int o = j / 144, r = j - o * 144;
    wm[j] = wmask[o * 288 + h * 144 + r];
  }
  __syncthreads();
  int p = blockIdx.x * 64 + tid;
  int y = p / WID, x = p - y * WID;
  double a0 = 0.0, a1 = 0.0;
  for (int icl = 0; icl < 16; ++icl) {
    const float* pl = xlast + (size_t)(4 + h * 16 + icl) * HWs;
    #pragma unroll
    for (int dy = -1; dy <= 1; ++dy) {
      int gy = y + dy;
      if ((unsigned)gy < 224u) {
        #pragma unroll
        for (int dx = -1; dx <= 1; ++dx) {
          int gx = x + dx;
          if ((unsigned)gx < 224u) {
            double v = (double)pl[gy * WID + gx];
            int t = (dy + 1) * 3 + (dx + 1);
            a0 += (double)wm[icl * 9 + t] * v;
            a1 += (double)wm[144 + icl * 9 + t] * v;
          }
        }
      }
    }
  }
  if (h == 0) { a0 += (double)bmask[0]; a1 += (double)bmask[1]; }
  smnh[(size_t)(h * 2 + 0) * HWs + p] = (float)a0;
  smnh[(size_t)(h * 2 + 1) * HWs + p] = (float)a1;
}

// ---------------- K5: 2x bilinear upsample + mask compare (unchanged)
__global__ void k_upsample(const float* __restrict__ xlast, const float* __restrict__ smnh,
                           const float* __restrict__ smask, float* __restrict__ out) {
  int q = blockIdx.x * 256 + threadIdx.x;
  int oy = q / 448, ox = q - oy * 448;
  int ky = oy >> 1, kx = ox >> 1;
  int r0, r1, c0, c1; float wy0, wy1, wx0, wx1;
  if (oy & 1) { r0 = ky; r1 = (ky < 223) ? ky + 1 : 223; wy0 = 0.75f; wy1 = 0.25f; }
  else        { r0 = (ky > 0) ? ky - 1 : 0; r1 = ky;     wy0 = 0.25f; wy1 = 0.75f; }
  if (ox & 1) { c0 = kx; c1 = (kx < 223) ? kx + 1 : 223; wx0 = 0.75f; wx1 = 0.25f; }
  else        { c0 = (kx > 0) ? kx - 1 : 0; c1 = kx;     wx0 = 0.25f; wx1 = 0.75f; }
  float w00 = wy0 * wx0, w01 = wy0 * wx1, w10 = wy1 * wx0, w11 = wy1 * wx1;
  int i00 = r0 * WID + c0, i01 = r0 * WID + c1, i10 = r1 * WID + c0, i11 = r1 * WID + c1;
  for (int ch = 0; ch < 36; ++ch) {
    const float* pl = xlast + (size_t)ch * HWs;
    out[(size_t)ch * OHW + q] = w00 * pl[i00] + w01 * pl[i01]
                              + w10 * pl[i10] + w11 * pl[i11];
  }
  const float* sa0 = smnh;
  const float* sa1 = smnh + HWs;
  const float* sb0 = smnh + 2 * HWs;
  const float* sb1 = smnh + 3 * HWs;
  double s0 = (double)w00 * ((double)sa0[i00] + (double)sb0[i00])
            + (double)w01 * ((double)sa0[i01] + (double)sb0[i01])
            + (double)w10 * ((double)sa0[i10] + (double)sb0[i10])
            + (double)w11 * ((double)sa0[i11] + (double)sb0[i11]);
  double s1 = (double)w00 * ((double)sa1[i00] + (double)sb1[i00])
            + (double)w01 * ((double)sa1[i01] + (double)sb1[i01])
            + (double)w10 * ((double)sa1[i10] + (double)sb1[i10])
            + (double)w11 * ((double)sa1[i11] + (double)sb1[i11]);
  float mu = smask[ky * WID + kx];
  out[36 * OHW + q] = (s0 > s1) ? mu : 0.f;
}

extern "C" void kernel_launch(void* const* d_in, const int* in_sizes, int n_in,
                              void* d_out, int out_size, void* d_ws, size_t ws_size,
                              hipStream_t stream) {
  const float* feat0   = (const float*)d_in[0];
  const float* feat1   = (const float*)d_in[1];
  const float* featd   = (const float*)d_in[2];
  const float* flow    = (const float*)d_in[3];
  const float* smask   = (const float*)d_in[4];
  const float* w_head  = (const float*)d_in[5];
  const float* a_head  = (const float*)d_in[6];
  const float* w_blk   = (const float*)d_in[7];
  const float* a_blk   = (const float*)d_in[8];
  const float* w_last  = (const float*)d_in[9];
  const float* b_last  = (const float*)d_in[10];
  const float* w_mask  = (const float*)d_in[11];
  const float* b_mask  = (const float*)d_in[12];

  // ws: 3 rotating X-format activation buffers (22.5MB each) + xlast + smnh + wlT + bw
  // total ~78.5 MB (previous rounds used ~110 MB fine).
  unsigned char* base = (unsigned char*)d_ws;
  const size_t XSZ = (size_t)HWs * XP;              // 22,478,848 B
  unsigned char* X0 = base;
  unsigned char* X1 = X0 + XSZ;
  unsigned char* X2 = X1 + XSZ;
  float* xlast = (float*)(X2 + XSZ);                // 36 planes f32
  float* smnh  = xlast + (size_t)36 * HWs;          // 4 planes
  float* wlT   = smnh + (size_t)4 * HWs;            // 18000 floats
  unsigned short* bw = (unsigned short*)(wlT + 18000);  // 5*294912 ushorts

  k_wt<<<dim3(720), 256, 0, stream>>>(w_head, w_blk, bw);
  k_wlT<<<dim3(71), 256, 0, stream>>>(w_last, wlT);
  k_binit<<<dim3(196, 36), 256, 0, stream>>>(b_last, xlast);
  k_warp<<<dim3(196, 4), 256, 0, stream>>>(feat0, feat1, featd, flow, X0);

  dim3 cgrid(7, 56);
  // 3-buffer rotation; esum launched when its input buffers are final.
  k_conv<<<cgrid, 256, 0, stream>>>(X0, bw,              a_head,      smask, X1);  // L0
  k_conv<<<cgrid, 256, 0, stream>>>(X1, bw + 1 * 294912, a_blk,       smask, X2);  // L1
  k_esum<<<dim3(784, 2), 64, 0, stream>>>(X1, X2, X2, wlT, xlast, 0);              // L0,L1
  k_conv<<<cgrid, 256, 0, stream>>>(X2, bw + 2 * 294912, a_blk + 100, smask, X0);  // L2
  k_conv<<<cgrid, 256, 0, stream>>>(X0, bw + 3 * 294912, a_blk + 200, smask, X1);  // L3
  k_conv<<<cgrid, 256, 0, stream>>>(X1, bw + 4 * 294912, a_blk + 300, smask, X2);  // L4
  k_esum<<<dim3(784, 3), 64, 0, stream>>>(X0, X1, X2, wlT, xlast, 2);              // L2-L4

  k_smn<<<dim3(784, 2), 64, 0, stream>>>(xlast, w_mask, b_mask, smnh);
  k_upsample<<<784, 256, 0, stream>>>(xlast, smnh, smask, (float*)d_out);
}

// Round 9
// 649.737 us; speedup vs baseline: 1.1302x; 1.1302x over previous
//
#include <hip/hip_runtime.h>
#include <hip/hip_bf16.h>

#define HWs 50176      // 224*224
#define WID 224
#define OHW 200704     // 448*448
#define XP 448         // bytes per pixel in X format: [hi 112ch][lo 112ch] bf16
#define CHUNKS 204     // 6 rows * 34 cols per conv tile
#define UNITS 1632     // CHUNKS * 8 sixteen-byte slots

typedef __attribute__((ext_vector_type(8))) short s16x8;
typedef __attribute__((ext_vector_type(4))) float f32x4;

static __device__ __forceinline__ unsigned short f2bf(float x) {
  unsigned u = __float_as_uint(x);
  unsigned r = (u + 0x7fffu + ((u >> 16) & 1u)) >> 16;   // RNE
  return (unsigned short)r;
}
static __device__ __forceinline__ float bf2f(unsigned short b) {
  return __uint_as_float(((unsigned)b) << 16);
}

// direct global->LDS DMA, 16B per lane, no destination VGPRs (deep MLP)
static __device__ __forceinline__ void gload_lds16(const unsigned char* g, unsigned char* l) {
  __builtin_amdgcn_global_load_lds(
      (const __attribute__((address_space(1))) unsigned int*)g,
      (__attribute__((address_space(3))) unsigned int*)l, 16, 0, 0);
}

// ---------------- K0: pack conv weights into MFMA B-fragment order, split bf16 hi/lo.
// frag_id = l*288 + t*32 + ck*8 + nt; B[k][n]: n = nt*16+(lane&15), ic = ck*32+(lane>>4)*8+e.
// oc>=100 or ic>=100 -> 0 (zero-padding makes A-side garbage for ic>=112 harmless).
__global__ void k_wt(const float* __restrict__ w_head, const float* __restrict__ w_blk,
                     unsigned short* __restrict__ bw) {
  int gid = blockIdx.x * 256 + threadIdx.x;          // 720*256 == 184320 exact
  int frag = gid >> 7, rr = gid & 127;
  int spl = rr >> 6, lane = rr & 63;
  int l = frag / 288, q = frag - l * 288;
  int t = q / 32, q2 = q - t * 32;
  int ck = q2 >> 3, nt = q2 & 7;
  int oc = nt * 16 + (lane & 15);
  int kg = lane >> 4;
  const float* src = (l == 0) ? w_head : (w_blk + (size_t)(l - 1) * 90000);
  s16x8 outv;
  #pragma unroll
  for (int e = 0; e < 8; ++e) {
    int ic = ck * 32 + kg * 8 + e;
    float w = (oc < 100 && ic < 100) ? src[oc * 900 + ic * 9 + t] : 0.f;
    unsigned short h = f2bf(w);
    unsigned short lo = f2bf(w - bf2f(h));
    outv[e] = (short)(spl ? lo : h);
  }
  ((s16x8*)bw)[gid] = outv;
}

// ---------------- K0c: transpose w_last [36][500] -> wlT [500][36]; also zero the zpage.
__global__ void k_wlT(const float* __restrict__ wlast, float* __restrict__ wlT,
                      float* __restrict__ zpage) {
  int i = blockIdx.x * 256 + threadIdx.x;
  if (i < 18000) {
    int il = i / 36, o = i - il * 36;
    wlT[i] = wlast[o * 500 + il];
  } else if (i < 18064) {
    zpage[i - 18000] = 0.f;                          // 256B zero page for OOB halo DMA
  }
}

// ---------------- K0b: xlast = b_last (k_esum atomically accumulates).
__global__ void k_binit(const float* __restrict__ blast, float* __restrict__ xlast) {
  int p = blockIdx.x * 256 + threadIdx.x;
  xlast[(size_t)blockIdx.y * HWs + p] = blast[blockIdx.y];
}

// ---------------- K1: bilinear warp + concat -> X-format (NHWC bf16 hi/lo).
__global__ void k_warp(const float* __restrict__ f0, const float* __restrict__ f1,
                       const float* __restrict__ fd, const float* __restrict__ fl,
                       unsigned char* __restrict__ xout) {
  int p = blockIdx.x * 256 + threadIdx.x;
  int yq = blockIdx.y;
  int y = p / WID, x = p - y * WID;
  float fx0 = fl[p];
  float fy0 = fl[HWs + p];
  float fx1 = fl[2 * HWs + p];
  float fy1 = fl[3 * HWs + p];
  unsigned char* dst = xout + (size_t)p * XP;

  auto cvstore = [&](int chbase, const float* ov) {
    s16x8 hv, lv;
    #pragma unroll
    for (int e = 0; e < 8; ++e) {
      unsigned short h = f2bf(ov[e]);
      hv[e] = (short)h;
      lv[e] = (short)f2bf(ov[e] - bf2f(h));
    }
    *(s16x8*)(dst + chbase * 2) = hv;
    *(s16x8*)(dst + 224 + chbase * 2) = lv;
  };

  #pragma unroll
  for (int img = 0; img < 2; ++img) {
    const float* src = img ? f1 : f0;
    float fx = img ? fx1 : fx0;
    float fy = img ? fy1 : fy0;
    float px = (float)x + fx, py = (float)y + fy;
    float x0f = floorf(px), y0f = floorf(py);
    float wx = px - x0f, wy = py - y0f;
    int x0 = (int)fminf(fmaxf(x0f,       0.f), 223.f);
    int x1 = (int)fminf(fmaxf(x0f + 1.f, 0.f), 223.f);
    int y0 = (int)fminf(fmaxf(y0f,       0.f), 223.f);
    int y1 = (int)fminf(fmaxf(y0f + 1.f, 0.f), 223.f);
    float w00 = (1.f - wx) * (1.f - wy), w01 = wx * (1.f - wy);
    float w10 = (1.f - wx) * wy,         w11 = wx * wy;
    int i00 = y0 * WID + x0, i01 = y0 * WID + x1;
    int i10 = y1 * WID + x0, i11 = y1 * WID + x1;
    float ov[8];
    #pragma unroll
    for (int e = 0; e < 8; ++e) {
      const float* pl = src + (size_t)(yq * 8 + e) * HWs;
      ov[e] = w00 * pl[i00] + w01 * pl[i01] + w10 * pl[i10] + w11 * pl[i11];
    }
    cvstore(img * 32 + yq * 8, ov);
  }
  {
    float ov[8];
    #pragma unroll
    for (int e = 0; e < 8; ++e)
      ov[e] = fd[(size_t)(yq * 8 + e) * HWs + p];
    cvstore(64 + yq * 8, ov);
  }
  if (yq == 0) {
    float ov[8] = {fx0, fy0, fx1, fy1, 0.f, 0.f, 0.f, 0.f};
    cvstore(96, ov);
    float zz[8] = {0.f, 0.f, 0.f, 0.f, 0.f, 0.f, 0.f, 0.f};
    cvstore(104, zz);
  }
}

// ---------------- K2: MFMA split-bf16 3x3 conv — global_load_lds DMA staging.
// grid (7,56) x 256: tile 4 rows x 32 cols x 128 oc; wave (wr,wz) = 2 rows x 64 oc.
// LDS: double-buffered 204 chunks x 128B (chunk = pixel's 32ic hi|lo for one ck),
// slot-level XOR swizzle (rc&7) applied on the SOURCE address (linear DMA dest) and
// on ds_read (rule #21). OOB halo -> zpage (zeros). Staging issued at ck end ->
// during taps only the 8-load B-prefetch is vmcnt-outstanding (static counted waits).
// MFMA order identical to rounds 1-8 -> conv outputs bit-identical.
__global__ __launch_bounds__(256) void k_conv(
    const unsigned char* __restrict__ in, const unsigned short* __restrict__ bw,
    const float* __restrict__ zpage,
    const float* __restrict__ avec, const float* __restrict__ mask,
    unsigned char* __restrict__ out) {
  __shared__ __align__(16) unsigned char sh[2][UNITS * 16];   // 2 x 26112 B
  const int tid = threadIdx.x;
  const int lane = tid & 63;
  const int wv = tid >> 6;
  const int wr = wv >> 1, wz = wv & 1;
  const int c0 = blockIdx.x * 32;
  const int r0 = blockIdx.y * 4;
  const int li = lane & 15, kg = lane >> 4;

  f32x4 acc[4][4];
  #pragma unroll
  for (int a = 0; a < 4; ++a)
    #pragma unroll
    for (int b = 0; b < 4; ++b) acc[a][b] = (f32x4){0.f, 0.f, 0.f, 0.f};

  const s16x8* bp = (const s16x8*)bw;
  s16x8 bcur[4][2], bnxt[4][2];
  #pragma unroll
  for (int nt = 0; nt < 4; ++nt)
    #pragma unroll
    for (int sp = 0; sp < 2; ++sp)
      bnxt[nt][sp] = bp[(((wz * 4 + nt) * 2 + sp) << 6) + lane];

  // stage ck's 32-ic slab: unit u -> LDS byte u*16 (linear DMA), source inverse-swizzled.
  // physical slot s of chunk rc holds logical l = s ^ (rc&7); l>>2: 0=hi,1=lo; l&3: kgs.
  auto STAGE = [&](int ck, int buf) {
    unsigned char* dst0 = &sh[buf][0];
    #pragma unroll
    for (int i = 0; i < 7; ++i) {
      int u = i * 256 + tid;
      if (u < UNITS) {
        int rc = u >> 3, s = u & 7;
        int pr = rc / 34, pc = rc - pr * 34;
        int gy = r0 - 1 + pr, gx = c0 - 1 + pc;
        int l = s ^ (rc & 7);
        int sect = l >> 2, kgs = l & 3;
        const unsigned char* g;
        if (((unsigned)gy < 224u) && ((unsigned)gx < 224u))
          g = in + (size_t)(gy * WID + gx) * XP + sect * 224 + ck * 64 + kgs * 16;
        else
          g = (const unsigned char*)zpage;
        gload_lds16(g, dst0 + (size_t)u * 16);
      }
    }
  };

  STAGE(0, 0);
  __syncthreads();                         // drains DMA (vmcnt 0) + aligns waves

  for (int ck = 0; ck < 4; ++ck) {
    const unsigned char* cur = sh[ck & 1];

    #pragma unroll
    for (int t = 0; t < 9; ++t) {
      #pragma unroll
      for (int nt = 0; nt < 4; ++nt) {
        bcur[nt][0] = bnxt[nt][0];
        bcur[nt][1] = bnxt[nt][1];
      }
      if (t < 8 || ck < 3) {
        int nf = (t < 8) ? (t + 1) * 32 + ck * 8 : (ck + 1) * 8;
        #pragma unroll
        for (int nt = 0; nt < 4; ++nt)
          #pragma unroll
          for (int sp = 0; sp < 2; ++sp)
            bnxt[nt][sp] = bp[(((nf + wz * 4 + nt) * 2 + sp) << 6) + lane];
      }
      const int dy = t / 3 - 1, dx = t - (t / 3) * 3 - 1;
      #pragma unroll
      for (int ms = 0; ms < 4; ++ms) {
        int pr = wr * 2 + (ms >> 1) + 1 + dy;
        int pc = (ms & 1) * 16 + li + 1 + dx;
        int rc = pr * 34 + pc;
        int base = rc * 128, sw = (rc & 7) << 4;
        s16x8 ah = *(const s16x8*)(cur + base + ((kg * 16) ^ sw));
        s16x8 al = *(const s16x8*)(cur + base + ((64 + kg * 16) ^ sw));
        #pragma unroll
        for (int nt = 0; nt < 4; ++nt) {
          acc[ms][nt] = __builtin_amdgcn_mfma_f32_16x16x32_bf16(ah, bcur[nt][0], acc[ms][nt], 0, 0, 0);
          acc[ms][nt] = __builtin_amdgcn_mfma_f32_16x16x32_bf16(al, bcur[nt][0], acc[ms][nt], 0, 0, 0);
          acc[ms][nt] = __builtin_amdgcn_mfma_f32_16x16x32_bf16(ah, bcur[nt][1], acc[ms][nt], 0, 0, 0);
        }
      }
    }
    if (ck < 3) {
      STAGE(ck + 1, (ck + 1) & 1);         // DMA issue: no VGPRs, deep in flight
      __syncthreads();                     // per-wave vmcnt(0) drain + visibility
    }
  }

  // epilogue: PReLU * mask, convert to hi/lo, store X-format.
  float4 mv[4];
  #pragma unroll
  for (int ms = 0; ms < 4; ++ms) {
    int row = r0 + wr * 2 + (ms >> 1);
    int colb = c0 + (ms & 1) * 16 + kg * 4;
    mv[ms] = *(const float4*)&mask[row * WID + colb];
  }
  #pragma unroll
  for (int nt = 0; nt < 4; ++nt) {
    int oc = wz * 64 + nt * 16 + li;
    if (oc < 112) {
      float a = (oc < 100) ? avec[oc] : 0.f;
      #pragma unroll
      for (int ms = 0; ms < 4; ++ms) {
        int row = r0 + wr * 2 + (ms >> 1);
        int colb = c0 + (ms & 1) * 16 + kg * 4;
        f32x4 zv = acc[ms][nt];
        float vv[4] = {zv.x, zv.y, zv.z, zv.w};
        float mm[4] = {mv[ms].x, mv[ms].y, mv[ms].z, mv[ms].w};
        #pragma unroll
        for (int e = 0; e < 4; ++e) {
          float v = (vv[e] >= 0.f ? vv[e] : a * vv[e]) * mm[e];
          unsigned short h = f2bf(v);
          unsigned short lo = f2bf(v - bf2f(h));
          unsigned char* d = out + (size_t)(row * WID + colb + e) * XP + oc * 2;
          *(unsigned short*)d = h;
          *(unsigned short*)(d + 224) = lo;
        }
      }
    }
  }
}

// ---------------- K3: einsum partial from X-format buffers, K-split by layer.
__global__ __launch_bounds__(64) void k_esum(
    const unsigned char* __restrict__ X0, const unsigned char* __restrict__ X1,
    const unsigned char* __restrict__ X2, const float* __restrict__ wlT,
    float* __restrict__ xlast, int lbase) {
  int p = blockIdx.x * 64 + threadIdx.x;
  int z = blockIdx.y;
  const unsigned char* X = (z == 0) ? X0 : (z == 1) ? X1 : X2;
  const unsigned char* a = X + (size_t)p * XP;
  const float* w = wlT + (size_t)(lbase + z) * 3600;
  float acc[36];
  #pragma unroll
  for (int o = 0; o < 36; ++o) acc[o] = 0.f;
  for (int cb = 0; cb < 100; cb += 8) {
    s16x8 hv = *(const s16x8*)(a + cb * 2);
    s16x8 lv = *(const s16x8*)(a + 224 + cb * 2);
    int ne = (cb < 96) ? 8 : 4;
    for (int e = 0; e < ne; ++e) {
      float v = bf2f((unsigned short)hv[e]) + bf2f((unsigned short)lv[e]);
      const float4* wp = (const float4*)(w + (cb + e) * 36);
      #pragma unroll
      for (int j = 0; j < 9; ++j) {
        float4 t = wp[j];
        acc[4*j]   = fmaf(t.x, v, acc[4*j]);
        acc[4*j+1] = fmaf(t.y, v, acc[4*j+1]);
        acc[4*j+2] = fmaf(t.z, v, acc[4*j+2]);
        acc[4*j+3] = fmaf(t.w, v, acc[4*j+3]);
      }
    }
  }
  #pragma unroll
  for (int o = 0; o < 36; ++o)
    atomicAdd(&xlast[(size_t)o * HWs + p], acc[o]);
}

// ---------------- K4: smn halves = conv3x3(xlast[4+h*16 .. +16], w_mask), fp64 accum.
__global__ void k_smn(const float* __restrict__ xlast, const float* __restrict__ wmask,
                      const float* __restrict__ bmask, float* __restrict__ smnh) {
  __shared__ float wm[288];
  int tid = threadIdx.x;
  int h = blockIdx.y;
  for (int j = tid; j < 288; j += 64) {
    int o = j / 144, r = j - o * 144;
    wm[j] = wmask[o * 288 + h * 144 + r];
  }
  __syncthreads();
  int p = blockIdx.x * 64 + tid;
  int y = p / WID, x = p - y * WID;
  double a0 = 0.0, a1 = 0.0;
  for (int icl = 0; icl < 16; ++icl) {
    const float* pl = xlast + (size_t)(4 + h * 16 + icl) * HWs;
    #pragma unroll
    for (int dy = -1; dy <= 1; ++dy) {
      int gy = y + dy;
      if ((unsigned)gy < 224u) {
        #pragma unroll
        for (int dx = -1; dx <= 1; ++dx) {
          int gx = x + dx;
          if ((unsigned)gx < 224u) {
            double v = (double)pl[gy * WID + gx];
            int t = (dy + 1) * 3 + (dx + 1);
            a0 += (double)wm[icl * 9 + t] * v;
            a1 += (double)wm[144 + icl * 9 + t] * v;
          }
        }
      }
    }
  }
  if (h == 0) { a0 += (double)bmask[0]; a1 += (double)bmask[1]; }
  smnh[(size_t)(h * 2 + 0) * HWs + p] = (float)a0;
  smnh[(size_t)(h * 2 + 1) * HWs + p] = (float)a1;
}

// ---------------- K5: 2x bilinear upsample + mask compare (unchanged)
__global__ void k_upsample(const float* __restrict__ xlast, const float* __restrict__ smnh,
                           const float* __restrict__ smask, float* __restrict__ out) {
  int q = blockIdx.x * 256 + threadIdx.x;
  int oy = q / 448, ox = q - oy * 448;
  int ky = oy >> 1, kx = ox >> 1;
  int r0, r1, c0, c1; float wy0, wy1, wx0, wx1;
  if (oy & 1) { r0 = ky; r1 = (ky < 223) ? ky + 1 : 223; wy0 = 0.75f; wy1 = 0.25f; }
  else        { r0 = (ky > 0) ? ky - 1 : 0; r1 = ky;     wy0 = 0.25f; wy1 = 0.75f; }
  if (ox & 1) { c0 = kx; c1 = (kx < 223) ? kx + 1 : 223; wx0 = 0.75f; wx1 = 0.25f; }
  else        { c0 = (kx > 0) ? kx - 1 : 0; c1 = kx;     wx0 = 0.25f; wx1 = 0.75f; }
  float w00 = wy0 * wx0, w01 = wy0 * wx1, w10 = wy1 * wx0, w11 = wy1 * wx1;
  int i00 = r0 * WID + c0, i01 = r0 * WID + c1, i10 = r1 * WID + c0, i11 = r1 * WID + c1;
  for (int ch = 0; ch < 36; ++ch) {
    const float* pl = xlast + (size_t)ch * HWs;
    out[(size_t)ch * OHW + q] = w00 * pl[i00] + w01 * pl[i01]
                              + w10 * pl[i10] + w11 * pl[i11];
  }
  const float* sa0 = smnh;
  const float* sa1 = smnh + HWs;
  const float* sb0 = smnh + 2 * HWs;
  const float* sb1 = smnh + 3 * HWs;
  double s0 = (double)w00 * ((double)sa0[i00] + (double)sb0[i00])
            + (double)w01 * ((double)sa0[i01] + (double)sb0[i01])
            + (double)w10 * ((double)sa0[i10] + (double)sb0[i10])
            + (double)w11 * ((double)sa0[i11] + (double)sb0[i11]);
  double s1 = (double)w00 * ((double)sa1[i00] + (double)sb1[i00])
            + (double)w01 * ((double)sa1[i01] + (double)sb1[i01])
            + (double)w10 * ((double)sa1[i10] + (double)sb1[i10])
            + (double)w11 * ((double)sa1[i11] + (double)sb1[i11]);
  float mu = smask[ky * WID + kx];
  out[36 * OHW + q] = (s0 > s1) ? mu : 0.f;
}

extern "C" void kernel_launch(void* const* d_in, const int* in_sizes, int n_in,
                              void* d_out, int out_size, void* d_ws, size_t ws_size,
                              hipStream_t stream) {
  const float* feat0   = (const float*)d_in[0];
  const float* feat1   = (const float*)d_in[1];
  const float* featd   = (const float*)d_in[2];
  const float* flow    = (const float*)d_in[3];
  const float* smask   = (const float*)d_in[4];
  const float* w_head  = (const float*)d_in[5];
  const float* a_head  = (const float*)d_in[6];
  const float* w_blk   = (const float*)d_in[7];
  const float* a_blk   = (const float*)d_in[8];
  const float* w_last  = (const float*)d_in[9];
  const float* b_last  = (const float*)d_in[10];
  const float* w_mask  = (const float*)d_in[11];
  const float* b_mask  = (const float*)d_in[12];

  // ws: 3 rotating X-format buffers + xlast + smnh + wlT + zpage + bw  (~78 MB)
  unsigned char* base = (unsigned char*)d_ws;
  const size_t XSZ = (size_t)HWs * XP;
  unsigned char* X0 = base;
  unsigned char* X1 = X0 + XSZ;
  unsigned char* X2 = X1 + XSZ;
  float* xlast = (float*)(X2 + XSZ);
  float* smnh  = xlast + (size_t)36 * HWs;
  float* wlT   = smnh + (size_t)4 * HWs;
  float* zpage = wlT + 18000;                            // 64 floats, zeroed by k_wlT
  unsigned short* bw = (unsigned short*)(zpage + 64);

  k_wt<<<dim3(720), 256, 0, stream>>>(w_head, w_blk, bw);
  k_wlT<<<dim3(71), 256, 0, stream>>>(w_last, wlT, zpage);
  k_binit<<<dim3(196, 36), 256, 0, stream>>>(b_last, xlast);
  k_warp<<<dim3(196, 4), 256, 0, stream>>>(feat0, feat1, featd, flow, X0);

  dim3 cgrid(7, 56);
  k_conv<<<cgrid, 256, 0, stream>>>(X0, bw,              zpage, a_head,      smask, X1);
  k_conv<<<cgrid, 256, 0, stream>>>(X1, bw + 1 * 294912, zpage, a_blk,       smask, X2);
  k_esum<<<dim3(784, 2), 64, 0, stream>>>(X1, X2, X2, wlT, xlast, 0);              // L0,L1
  k_conv<<<cgrid, 256, 0, stream>>>(X2, bw + 2 * 294912, zpage, a_blk + 100, smask, X0);
  k_conv<<<cgrid, 256, 0, stream>>>(X0, bw + 3 * 294912, zpage, a_blk + 200, smask, X1);
  k_conv<<<cgrid, 256, 0, stream>>>(X1, bw + 4 * 294912, zpage, a_blk + 300, smask, X2);
  k_esum<<<dim3(784, 3), 64, 0, stream>>>(X0, X1, X2, wlT, xlast, 2);              // L2-L4

  k_smn<<<dim3(784, 2), 64, 0, stream>>>(xlast, w_mask, b_mask, smnh);
  k_upsample<<<784, 256, 0, stream>>>(xlast, smnh, smask, (float*)d_out);
}